// Round 12
// baseline (211.535 us; speedup 1.0000x reference)
//
#include <hip/hip_runtime.h>
#include <hip/hip_bf16.h>

// Causal SDPA, B=8, S=4096, D=64, fp32 in/out.
// Outputs: O [8,4096,64] then attention P [8,4096,4096], concatenated in d_out.
//
// Round 11: raise k_pwrite_pv occupancy 2 -> 3 blocks/CU by single-buffering
// Ps (LDS 64KB -> 48KB). Cost: one extra barrier per tile (copy-out must
// complete before next tile's Ps writes). With 3 co-resident blocks the
// barrier stalls of one block hide under the others' store/compute phases;
// +50% concurrent store streams attacks the ~65%-of-write-ceiling plateau.
// Everything else identical to r10 (best-known structure, 207.6-209.5us).
//  k_rowsum   : QK^T(swapped)+exp+rowsum -> wsRow
//  k_pwrite_pv: zero-fill | normalize P -> Ps(bf16, SINGLE buf)
//               -> coalesced 256B-run stream; PV -> wsO (or O when nkc==1)
//  k_ored     : sum <=8 normalized partials -> O (nkc>1 only)

#define S_LEN 4096
#define D_DIM 64

typedef float f32x4 __attribute__((ext_vector_type(4)));
typedef short bf16x8 __attribute__((ext_vector_type(8)));
typedef unsigned short u16;
typedef unsigned long long u64;

// ws layout (floats): wsRow [8][32][8][128] = 262144,
//                     wsO [8][32][8][8192] = 16777216
#define WSROW_FLOATS (262144)
#define WSO_FLOATS   ((size_t)8 * 32 * 8 * 8192)

__device__ __forceinline__ u16 f2bf(float f) {
  union { float f; unsigned u; } x; x.f = f;
  unsigned r = x.u + 0x7fff + ((x.u >> 16) & 1);  // RNE
  return (u16)(r >> 16);
}
__device__ __forceinline__ float bf2f(short h) {
  return __uint_as_float(((unsigned)(unsigned short)h) << 16);
}
__device__ __forceinline__ bf16x8 pack8(f32x4 a, f32x4 b) {
  bf16x8 r;
  r[0] = (short)f2bf(a[0]); r[1] = (short)f2bf(a[1]);
  r[2] = (short)f2bf(a[2]); r[3] = (short)f2bf(a[3]);
  r[4] = (short)f2bf(b[0]); r[5] = (short)f2bf(b[1]);
  r[6] = (short)f2bf(b[2]); r[7] = (short)f2bf(b[3]);
  return r;
}
__device__ __forceinline__ unsigned pk2(float a, float b) {
  return (unsigned)f2bf(a) | ((unsigned)f2bf(b) << 16);
}

// legacy helpers (fallback kernel only)
__device__ __forceinline__ void stageK_fn(u16* Ks, const float* src, int t) {
  int linear = t;
#pragma unroll
  for (int j = 0; j < 4; ++j, linear += 256) {
    int r = linear >> 4, cq = linear & 15;
    f32x4 v = *(const f32x4*)(src + r * D_DIM + cq * 4);
    int byte = r * 128 + ((cq * 8) ^ ((r & 7) << 4));
    *(u64*)((char*)Ks + byte) =
        (u64)pk2(v[0], v[1]) | ((u64)pk2(v[2], v[3]) << 32);
  }
}
__device__ __forceinline__ void stageV_fn(u16* VTs, const float* src, int t) {
  int kk = t >> 2;
  int dbase = (t & 3) * 16;
  const float* s = src + (size_t)kk * D_DIM + dbase;
#pragma unroll
  for (int j4 = 0; j4 < 4; ++j4) {
    f32x4 v = *(const f32x4*)(s + j4 * 4);
#pragma unroll
    for (int e = 0; e < 4; ++e) {
      int d = dbase + j4 * 4 + e;
      int byte = d * 128 + ((kk * 2) ^ ((d & 7) << 4));
      *(u16*)((char*)VTs + byte) = f2bf(v[e]);
    }
  }
}

// 512-thread staging macros. K tile [64 krows][64 d] f32 -> bf16 swizzled.
#define LOADK_M(ktg_)                                                      \
  {                                                                        \
    const float* src_ = Kg + (size_t)(ktg_)*D_DIM;                         \
    _Pragma("unroll") for (int j = 0; j < 2; ++j) {                        \
      int lin = t + j * 512, r_ = lin >> 4, cq_ = lin & 15;                \
      kreg[j] = *(const f32x4*)(src_ + r_ * D_DIM + cq_ * 4);              \
    }                                                                      \
  }
#define WRITEK_M(buf_)                                                     \
  {                                                                        \
    _Pragma("unroll") for (int j = 0; j < 2; ++j) {                        \
      int lin = t + j * 512, r_ = lin >> 4, cq_ = lin & 15;                \
      int byte_ = r_ * 128 + ((cq_ * 8) ^ ((r_ & 7) << 4));                \
      *(u64*)((char*)(buf_) + byte_) =                                     \
          (u64)pk2(kreg[j][0], kreg[j][1]) |                               \
          ((u64)pk2(kreg[j][2], kreg[j][3]) << 32);                        \
    }                                                                      \
  }
// V tile: 8 k-rows per thread-group (vq=t>>6 in 0..7), lane vd=d (coalesced)
#define LOADV_M(ktg_)                                                      \
  {                                                                        \
    const float* src_ = Vg + (size_t)((ktg_) + vq * 8) * D_DIM + vd;       \
    _Pragma("unroll") for (int j = 0; j < 8; ++j)                          \
        vreg[j] = src_[j * D_DIM];                                         \
  }
#define WRITEV_M(buf_)                                                     \
  {                                                                        \
    uint4 a_;                                                              \
    a_.x = pk2(vreg[0], vreg[1]); a_.y = pk2(vreg[2], vreg[3]);            \
    a_.z = pk2(vreg[4], vreg[5]); a_.w = pk2(vreg[6], vreg[7]);            \
    int swz_ = (vd & 7) << 4;                                              \
    *(uint4*)((char*)(buf_) + vd * 128 + ((vq * 16) ^ swz_)) = a_;         \
  }

// ---------------- kernel 1: partial rowsums (128 q-rows/block) ---------------
__global__ void __launch_bounds__(512) k_rowsum(
    const float* __restrict__ Q, const float* __restrict__ K,
    float* __restrict__ wsRow) {
  __shared__ __align__(16) u16 Ks[2][64 * 64];

  const int t = threadIdx.x, lane = t & 63, w = t >> 6;
  const int cl = lane & 15, lg = lane >> 4;
  const int bx = blockIdx.x;
  const int qt2 = 31 - (bx >> 6);      // heavy first
  const int b = (bx >> 3) & 7;
  const int kc = bx & 7;
  const int q0 = qt2 * 128;
  if (kc * 512 > q0 + 127) return;     // chunk fully above diagonal

  const float* Qg = Q + ((size_t)b * S_LEN + q0) * D_DIM;
  const float* Kg = K + (size_t)b * S_LEN * D_DIM;

  f32x4 kreg[2];
  LOADK_M(kc * 512);                   // tile-0 loads in flight

  const int qrl = w * 16 + cl;         // this lane's q-row (0..127)
  const int qglob = q0 + qrl;
  f32x4 qv0 = *(const f32x4*)(Qg + qrl * D_DIM + lg * 8);
  f32x4 qv1 = *(const f32x4*)(Qg + qrl * D_DIM + lg * 8 + 4);
  f32x4 qv2 = *(const f32x4*)(Qg + qrl * D_DIM + 32 + lg * 8);
  f32x4 qv3 = *(const f32x4*)(Qg + qrl * D_DIM + 32 + lg * 8 + 4);
  bf16x8 bq0 = pack8(qv0, qv1), bq1 = pack8(qv2, qv3);

  const int nt = min(8, ((q0 + 127 - kc * 512) >> 6) + 1);

  WRITEK_M(Ks[0]);
  __syncthreads();

  float psum = 0.f;
  int cur = 0;
  for (int ct64 = 0; ct64 < nt; ++ct64) {
    const int ktg = kc * 512 + ct64 * 64;
    const bool hasNext = (ct64 + 1 < nt);
    if (hasNext) LOADK_M(ktg + 64);
    const u16* Kb = Ks[cur];
#pragma unroll
    for (int ct = 0; ct < 4; ++ct) {
      int krow = ct * 16 + cl;
      int bb0 = krow * 128 + ((lg * 16) ^ ((krow & 7) << 4));
      int bb1 = krow * 128 + ((64 + lg * 16) ^ ((krow & 7) << 4));
      bf16x8 ak0 = *(const bf16x8*)((const char*)Kb + bb0);
      bf16x8 ak1 = *(const bf16x8*)((const char*)Kb + bb1);
      f32x4 c = {0.f, 0.f, 0.f, 0.f};
      c = __builtin_amdgcn_mfma_f32_16x16x32_bf16(ak0, bq0, c, 0, 0, 0);
      c = __builtin_amdgcn_mfma_f32_16x16x32_bf16(ak1, bq1, c, 0, 0, 0);
#pragma unroll
      for (int r = 0; r < 4; ++r) {
        float ev = __expf(c[r] * 0.125f);
        if ((ktg + ct * 16 + lg * 4 + r) > qglob) ev = 0.f;  // causal
        psum += ev;
      }
    }
    if (hasNext) WRITEK_M(Ks[cur ^ 1]);
    __syncthreads();
    cur ^= 1;
  }

  psum += __shfl_xor(psum, 16, 64);
  psum += __shfl_xor(psum, 32, 64);
  const int slot = ((b * 32 + qt2) * 8 + kc);
  if (lg == 0) wsRow[(size_t)slot * 128 + qrl] = psum;
}

// -------- kernel 2: P (LDS-coalesced stream) + PV -> O partials / O ----------
__global__ void __launch_bounds__(512) k_pwrite_pv(
    const float* __restrict__ Q, const float* __restrict__ K,
    const float* __restrict__ V, const float* __restrict__ wsRow,
    float* __restrict__ Pg, float* __restrict__ wsO,
    float* __restrict__ Og) {
  __shared__ __align__(16) u16 Ks[2][64 * 64];
  __shared__ __align__(16) u16 VTs[2][64 * 64];
  __shared__ __align__(16) u16 Ps[128 * 64];   // SINGLE buffer (48KB total LDS)

  const int t = threadIdx.x, lane = t & 63, w = t >> 6;
  const int cl = lane & 15, lg = lane >> 4;
  const int bx = blockIdx.x;
  const int qt2 = 31 - (bx >> 6);
  const int b = (bx >> 3) & 7;
  const int kc = bx & 7;
  const int q0 = qt2 * 128;
  float* PgB = Pg + ((size_t)b * S_LEN + q0) * S_LEN + kc * 512;

  if (kc * 512 > q0 + 127) {  // fully above diagonal: pure zero-fill, 256KB
    f32x4 z = {0.f, 0.f, 0.f, 0.f};
    for (int idx = t; idx < 16384; idx += 512)
      *((f32x4*)(PgB + (size_t)(idx >> 7) * S_LEN) + (idx & 127)) = z;
    return;
  }

  const float* Qg = Q + ((size_t)b * S_LEN + q0) * D_DIM;
  const float* Kg = K + (size_t)b * S_LEN * D_DIM;
  const float* Vg = V + (size_t)b * S_LEN * D_DIM;

  // issue tile-0 staging loads FIRST; zero-fill + rl computation hide them
  f32x4 kreg[2];
  float vreg[8];
  const int vd = t & 63, vq = t >> 6;
  LOADK_M(kc * 512);
  LOADV_M(kc * 512);

  const int nt = min(8, ((q0 + 127 - kc * 512) >> 6) + 1);
  if (nt < 8) {  // zero-fill tail cols [nt*64, 512) for all 128 rows
    const int zc4 = (8 - nt) * 16;  // f32x4 per row (multiple of 16)
    f32x4 z = {0.f, 0.f, 0.f, 0.f};
    for (int r = (t >> 4); r < 128; r += 32) {
      f32x4* rowp = (f32x4*)(PgB + (size_t)r * S_LEN + nt * 64);
      for (int c = (t & 15); c < zc4; c += 16) rowp[c] = z;
    }
  }

  // 1/l for this lane's q-row
  const int nkc = (qt2 >> 2) + 1;
  const float* rowbase = wsRow + (size_t)(b * 32 + qt2) * 8 * 128;
  const int qrl = w * 16 + cl;
  const int qglob = q0 + qrl;
  float ls = 0.f;
  for (int k2 = 0; k2 < nkc; ++k2) ls += rowbase[k2 * 128 + qrl];
  const float rl = 1.0f / ls;

  f32x4 qv0 = *(const f32x4*)(Qg + qrl * D_DIM + lg * 8);
  f32x4 qv1 = *(const f32x4*)(Qg + qrl * D_DIM + lg * 8 + 4);
  f32x4 qv2 = *(const f32x4*)(Qg + qrl * D_DIM + 32 + lg * 8);
  f32x4 qv3 = *(const f32x4*)(Qg + qrl * D_DIM + 32 + lg * 8 + 4);
  bf16x8 bq0 = pack8(qv0, qv1), bq1 = pack8(qv2, qv3);

  WRITEK_M(Ks[0]);
  WRITEV_M(VTs[0]);
  __syncthreads();

  f32x4 oacc[4];
#pragma unroll
  for (int dt = 0; dt < 4; ++dt) oacc[dt] = (f32x4){0.f, 0.f, 0.f, 0.f};

  int cur = 0;
  for (int ct64 = 0; ct64 < nt; ++ct64) {
    const int ktg = kc * 512 + ct64 * 64;
    const bool hasNext = (ct64 + 1 < nt);
    if (hasNext) {  // issue next-tile loads under this tile's compute (T14)
      LOADK_M(ktg + 64);
      LOADV_M(ktg + 64);
    }
    const u16* Kb = Ks[cur];
    const u16* Vb = VTs[cur];

    // swapped QK^T: lane owns q-row qrl, 4 consecutive k per subtile.
    // Normalized P -> Ps (bf16, packed b64); NO direct global store here.
#pragma unroll
    for (int ct = 0; ct < 4; ++ct) {
      int krow = ct * 16 + cl;
      int bb0 = krow * 128 + ((lg * 16) ^ ((krow & 7) << 4));
      int bb1 = krow * 128 + ((64 + lg * 16) ^ ((krow & 7) << 4));
      bf16x8 ak0 = *(const bf16x8*)((const char*)Kb + bb0);
      bf16x8 ak1 = *(const bf16x8*)((const char*)Kb + bb1);
      f32x4 c = {0.f, 0.f, 0.f, 0.f};
      c = __builtin_amdgcn_mfma_f32_16x16x32_bf16(ak0, bq0, c, 0, 0, 0);
      c = __builtin_amdgcn_mfma_f32_16x16x32_bf16(ak1, bq1, c, 0, 0, 0);
      f32x4 p;
#pragma unroll
      for (int r = 0; r < 4; ++r) {
        float e = __expf(c[r] * 0.125f);
        if ((ktg + ct * 16 + lg * 4 + r) > qglob) e = 0.f;  // causal
        p[r] = e * rl;
      }
      int pbyte = qrl * 128 + (((ct * 32 + lg * 8)) ^ ((qrl & 7) << 4));
      *(u64*)((char*)Ps + pbyte) =
          (u64)pk2(p[0], p[1]) | ((u64)pk2(p[2], p[3]) << 32);
    }

    // PV with normalized P (same-wave rows of Ps) -> O partials
    {
      int pb0 = qrl * 128 + ((lg * 16) ^ ((qrl & 7) << 4));
      int pb1 = qrl * 128 + ((64 + lg * 16) ^ ((qrl & 7) << 4));
      bf16x8 pa0 = *(const bf16x8*)((const char*)Ps + pb0);
      bf16x8 pa1 = *(const bf16x8*)((const char*)Ps + pb1);
#pragma unroll
      for (int dt = 0; dt < 4; ++dt) {
        int vrow = dt * 16 + cl;
        int vb0 = vrow * 128 + ((lg * 16) ^ ((vrow & 7) << 4));
        int vb1 = vrow * 128 + ((64 + lg * 16) ^ ((vrow & 7) << 4));
        bf16x8 v0 = *(const bf16x8*)((const char*)Vb + vb0);
        bf16x8 v1 = *(const bf16x8*)((const char*)Vb + vb1);
        oacc[dt] = __builtin_amdgcn_mfma_f32_16x16x32_bf16(pa0, v0, oacc[dt], 0, 0, 0);
        oacc[dt] = __builtin_amdgcn_mfma_f32_16x16x32_bf16(pa1, v1, oacc[dt], 0, 0, 0);
      }
    }

    if (hasNext) {  // write prefetched tile AFTER compute (T14)
      WRITEK_M(Ks[cur ^ 1]);
      WRITEV_M(VTs[cur ^ 1]);
    }
    __syncthreads();  // all Ps writes + staged K/V visible

    // ---- coalesced copy-out of Ps: 16 lanes per row -> 256B segments ----
#pragma unroll
    for (int j = 0; j < 4; ++j) {
      int slot = j * 512 + t;
      int row = slot >> 4, c4 = slot & 15;
      int byte = row * 128 + ((c4 * 8) ^ ((row & 7) << 4));
      u64 pk = *(const u64*)((const char*)Ps + byte);
      f32x4 o;
      o[0] = bf2f((short)(pk & 0xffff));
      o[1] = bf2f((short)((pk >> 16) & 0xffff));
      o[2] = bf2f((short)((pk >> 32) & 0xffff));
      o[3] = bf2f((short)(pk >> 48));
      *(f32x4*)(PgB + (size_t)row * S_LEN + ct64 * 64 + c4 * 4) = o;
    }
    __syncthreads();  // copy-out complete before next tile overwrites Ps
    cur ^= 1;
  }

  if (nkc == 1) {
    // single k-chunk: this block owns the whole row -> write O directly
    float* dstO = Og + ((size_t)b * S_LEN + q0) * D_DIM;
#pragma unroll
    for (int dt = 0; dt < 4; ++dt)
#pragma unroll
      for (int r = 0; r < 4; ++r)
        dstO[(w * 16 + lg * 4 + r) * 64 + dt * 16 + cl] = oacc[dt][r];
  } else {
    const int slot = ((b * 32 + qt2) * 8 + kc);
    float* dstO = wsO + (size_t)slot * 8192;
#pragma unroll
    for (int dt = 0; dt < 4; ++dt)
#pragma unroll
      for (int r = 0; r < 4; ++r)
        dstO[(w * 16 + lg * 4 + r) * 64 + dt * 16 + cl] = oacc[dt][r];
  }
}

// ---------------- kernel 3: sum O partials (already normalized) --------------
__global__ void __launch_bounds__(256) k_ored(
    const float* __restrict__ wsO, float* __restrict__ Og) {
  const int bx = blockIdx.x;
  const int b = bx & 7, qt2 = bx >> 3;
  const int nkc = (qt2 >> 2) + 1;
  if (nkc == 1) return;  // written directly by k_pwrite_pv
  const int t = threadIdx.x;
  const f32x4* src = (const f32x4*)(wsO + (size_t)(b * 32 + qt2) * 8 * 8192);
  f32x4* dst = (f32x4*)(Og + ((size_t)b * S_LEN + qt2 * 128) * D_DIM);
  for (int i = t; i < 2048; i += 256) {
    f32x4 s = {0.f, 0.f, 0.f, 0.f};
    for (int k2 = 0; k2 < nkc; ++k2) s += src[k2 * 2048 + i];
    dst[i] = s;
  }
}

// ---------------- round-0 fallback (used only if ws too small) ----------------
__global__ void __launch_bounds__(256) attn_kernel(
    const float* __restrict__ Q, const float* __restrict__ K,
    const float* __restrict__ V, float* __restrict__ Og,
    float* __restrict__ Pg) {
  __shared__ __align__(16) u16 Qs[64 * 64];
  __shared__ __align__(16) u16 Ksh[64 * 64];
  __shared__ __align__(16) u16 VTs[64 * 64];
  __shared__ __align__(16) u16 Ps[64 * 64];

  const int t = threadIdx.x;
  const int lane = t & 63;
  const int w = t >> 6;
  const int cl = lane & 15;
  const int lg = lane >> 4;
  const int bx = blockIdx.x;
  const int b = bx & 7;
  const int qb = 63 - (bx >> 3);
  const int q0 = qb * 64;

  const float* Qg = Q + ((size_t)b * S_LEN + q0) * D_DIM;
  const float* Kg = K + (size_t)b * S_LEN * D_DIM;
  const float* Vg = V + (size_t)b * S_LEN * D_DIM;
  float* PgB = Pg + ((size_t)b * S_LEN + q0) * S_LEN;

  {
    int zc4 = (63 - qb) * 16;
    if (zc4 > 0) {
      f32x4 z = {0.f, 0.f, 0.f, 0.f};
      for (int r = 0; r < 64; ++r) {
        f32x4* rowp = (f32x4*)(PgB + (size_t)r * S_LEN + (size_t)(qb + 1) * 64);
        for (int c = t; c < zc4; c += 256) rowp[c] = z;
      }
    }
  }
  stageK_fn(Qs, Qg, t);
  __syncthreads();
  const int qrow = w * 16 + cl;
  bf16x8 aq0, aq1;
  {
    int b0 = qrow * 128 + ((lg * 16) ^ ((qrow & 7) << 4));
    int b1 = qrow * 128 + ((64 + lg * 16) ^ ((qrow & 7) << 4));
    aq0 = *(const bf16x8*)((char*)Qs + b0);
    aq1 = *(const bf16x8*)((char*)Qs + b1);
  }
  float psum[4] = {0.f, 0.f, 0.f, 0.f};
  for (int kt = 0; kt <= qb; ++kt) {
    __syncthreads();
    stageK_fn(Ksh, Kg + (size_t)kt * 64 * D_DIM, t);
    __syncthreads();
#pragma unroll
    for (int ct = 0; ct < 4; ++ct) {
      int krow = ct * 16 + cl;
      int bb0 = krow * 128 + ((lg * 16) ^ ((krow & 7) << 4));
      int bb1 = krow * 128 + ((64 + lg * 16) ^ ((krow & 7) << 4));
      bf16x8 bk0 = *(const bf16x8*)((char*)Ksh + bb0);
      bf16x8 bk1 = *(const bf16x8*)((char*)Ksh + bb1);
      f32x4 c = {0.f, 0.f, 0.f, 0.f};
      c = __builtin_amdgcn_mfma_f32_16x16x32_bf16(aq0, bk0, c, 0, 0, 0);
      c = __builtin_amdgcn_mfma_f32_16x16x32_bf16(aq1, bk1, c, 0, 0, 0);
      int colg = kt * 64 + ct * 16 + cl;
      int rowbase = q0 + w * 16 + lg * 4;
#pragma unroll
      for (int r = 0; r < 4; ++r) {
        float e = 0.f;
        if (colg <= rowbase + r) e = __expf(c[r] * 0.125f);
        psum[r] += e;
      }
    }
  }
  float rl[4];
#pragma unroll
  for (int r = 0; r < 4; ++r) {
    float s = psum[r];
    s += __shfl_xor(s, 1, 64);
    s += __shfl_xor(s, 2, 64);
    s += __shfl_xor(s, 4, 64);
    s += __shfl_xor(s, 8, 64);
    rl[r] = 1.0f / s;
  }
  f32x4 oacc[4];
#pragma unroll
  for (int dt = 0; dt < 4; ++dt) oacc[dt] = (f32x4){0.f, 0.f, 0.f, 0.f};
  for (int kt = 0; kt <= qb; ++kt) {
    __syncthreads();
    stageK_fn(Ksh, Kg + (size_t)kt * 64 * D_DIM, t);
    stageV_fn(VTs, Vg + (size_t)kt * 64 * D_DIM, t);
    __syncthreads();
#pragma unroll
    for (int ct = 0; ct < 4; ++ct) {
      int krow = ct * 16 + cl;
      int bb0 = krow * 128 + ((lg * 16) ^ ((krow & 7) << 4));
      int bb1 = krow * 128 + ((64 + lg * 16) ^ ((krow & 7) << 4));
      bf16x8 bk0 = *(const bf16x8*)((char*)Ksh + bb0);
      bf16x8 bk1 = *(const bf16x8*)((char*)Ksh + bb1);
      f32x4 c = {0.f, 0.f, 0.f, 0.f};
      c = __builtin_amdgcn_mfma_f32_16x16x32_bf16(aq0, bk0, c, 0, 0, 0);
      c = __builtin_amdgcn_mfma_f32_16x16x32_bf16(aq1, bk1, c, 0, 0, 0);
      int colg = kt * 64 + ct * 16 + cl;
      int rowl = w * 16 + lg * 4;
#pragma unroll
      for (int r = 0; r < 4; ++r) {
        float e = 0.f;
        if (colg <= q0 + rowl + r) e = __expf(c[r] * 0.125f);
        float p = e * rl[r];
        int pr = rowl + r;
        int byte = pr * 128 + ((((ct * 16 + cl) * 2)) ^ ((pr & 7) << 4));
        *(u16*)((char*)Ps + byte) = f2bf(p);
      }
    }
    __syncthreads();
    {
      int prow = w * 16 + cl;
      int pb0 = prow * 128 + ((lg * 16) ^ ((prow & 7) << 4));
      int pb1 = prow * 128 + ((64 + lg * 16) ^ ((prow & 7) << 4));
      bf16x8 pa0 = *(const bf16x8*)((char*)Ps + pb0);
      bf16x8 pa1 = *(const bf16x8*)((char*)Ps + pb1);
#pragma unroll
      for (int dt = 0; dt < 4; ++dt) {
        int vrow = dt * 16 + cl;
        int vb0 = vrow * 128 + ((lg * 16) ^ ((vrow & 7) << 4));
        int vb1 = vrow * 128 + ((64 + lg * 16) ^ ((vrow & 7) << 4));
        bf16x8 v0 = *(const bf16x8*)((char*)VTs + vb0);
        bf16x8 v1 = *(const bf16x8*)((char*)VTs + vb1);
        oacc[dt] = __builtin_amdgcn_mfma_f32_16x16x32_bf16(pa0, v0, oacc[dt], 0, 0, 0);
        oacc[dt] = __builtin_amdgcn_mfma_f32_16x16x32_bf16(pa1, v1, oacc[dt], 0, 0, 0);
      }
    }
#pragma unroll
    for (int j = 0; j < 2; ++j) {
      int idx = j * 256 + t;
      int pr = idx >> 3, c8 = idx & 7;
      int byte = pr * 128 + ((c8 * 16) ^ ((pr & 7) << 4));
      bf16x8 pv = *(const bf16x8*)((char*)Ps + byte);
      f32x4 f0, f1;
#pragma unroll
      for (int e = 0; e < 4; ++e) {
        f0[e] = bf2f(pv[e]);
        f1[e] = bf2f(pv[4 + e]);
      }
      f32x4* dst = (f32x4*)(PgB + (size_t)pr * S_LEN + kt * 64 + c8 * 8);
      dst[0] = f0;
      dst[1] = f1;
    }
  }
#pragma unroll
  for (int dt = 0; dt < 4; ++dt)
#pragma unroll
    for (int r = 0; r < 4; ++r)
      Og[((size_t)b * S_LEN + q0 + w * 16 + lg * 4 + r) * D_DIM + dt * 16 + cl] =
          oacc[dt][r];
}

extern "C" void kernel_launch(void* const* d_in, const int* in_sizes, int n_in,
                              void* d_out, int out_size, void* d_ws, size_t ws_size,
                              hipStream_t stream) {
  (void)in_sizes; (void)n_in; (void)out_size;
  const float* Q = (const float*)d_in[0];
  const float* K = (const float*)d_in[1];
  const float* V = (const float*)d_in[2];
  float* Og = (float*)d_out;
  float* Pg = (float*)d_out + (size_t)8 * S_LEN * D_DIM;

  const size_t need = (WSROW_FLOATS + WSO_FLOATS) * sizeof(float);
  if (d_ws != nullptr && ws_size >= need) {
    float* wsRow = (float*)d_ws;
    float* wsO = wsRow + WSROW_FLOATS;
    hipLaunchKernelGGL(k_rowsum, dim3(2048), dim3(512), 0, stream, Q, K, wsRow);
    hipLaunchKernelGGL(k_pwrite_pv, dim3(2048), dim3(512), 0, stream,
                       Q, K, V, wsRow, Pg, wsO, Og);
    hipLaunchKernelGGL(k_ored, dim3(256), dim3(256), 0, stream, wsO, Og);
  } else {
    hipLaunchKernelGGL(attn_kernel, dim3(512), dim3(256), 0, stream, Q, K, V, Og, Pg);
  }
}

// Round 13
// 198.647 us; speedup vs baseline: 1.0649x; 1.0649x over previous
//
#include <hip/hip_runtime.h>
#include <hip/hip_bf16.h>

// Causal SDPA, B=8, S=4096, D=64, fp32 in/out.
// Outputs: O [8,4096,64] then attention P [8,4096,4096], concatenated in d_out.
//
// Round 12: r10 structure (best family, 207.6-209.5us) + NONTEMPORAL stores
// for all write-once streams (P copy-out, zero-fill, wsO/O partials) and
// nontemporal loads of wsO in k_ored. Mechanism: the 537MB P stream currently
// write-allocates in the 4MB per-XCD L2s, thrashing staging-load locality and
// L2 write paths; `nt` bypasses allocate. Last single-variable lever; if
// neutral, the ~208us plateau is the structure's roofline.
//  k_rowsum   : QK^T(swapped)+exp+rowsum -> wsRow
//  k_pwrite_pv: zero-fill | normalize P -> Ps(bf16,dbuf) -> coalesced nt
//               stream; PV -> wsO (or O when nkc==1)
//  k_ored     : sum <=8 normalized partials -> O (nkc>1 only)

#define S_LEN 4096
#define D_DIM 64

typedef float f32x4 __attribute__((ext_vector_type(4)));
typedef short bf16x8 __attribute__((ext_vector_type(8)));
typedef unsigned short u16;
typedef unsigned long long u64;

// ws layout (floats): wsRow [8][32][8][128] = 262144,
//                     wsO [8][32][8][8192] = 16777216
#define WSROW_FLOATS (262144)
#define WSO_FLOATS   ((size_t)8 * 32 * 8 * 8192)

__device__ __forceinline__ u16 f2bf(float f) {
  union { float f; unsigned u; } x; x.f = f;
  unsigned r = x.u + 0x7fff + ((x.u >> 16) & 1);  // RNE
  return (u16)(r >> 16);
}
__device__ __forceinline__ float bf2f(short h) {
  return __uint_as_float(((unsigned)(unsigned short)h) << 16);
}
__device__ __forceinline__ bf16x8 pack8(f32x4 a, f32x4 b) {
  bf16x8 r;
  r[0] = (short)f2bf(a[0]); r[1] = (short)f2bf(a[1]);
  r[2] = (short)f2bf(a[2]); r[3] = (short)f2bf(a[3]);
  r[4] = (short)f2bf(b[0]); r[5] = (short)f2bf(b[1]);
  r[6] = (short)f2bf(b[2]); r[7] = (short)f2bf(b[3]);
  return r;
}
__device__ __forceinline__ unsigned pk2(float a, float b) {
  return (unsigned)f2bf(a) | ((unsigned)f2bf(b) << 16);
}
__device__ __forceinline__ void nt_store4(float* p, f32x4 v) {
  __builtin_nontemporal_store(v, (f32x4*)p);
}
__device__ __forceinline__ void nt_store1(float* p, float v) {
  __builtin_nontemporal_store(v, p);
}

// legacy helpers (fallback kernel only)
__device__ __forceinline__ void stageK_fn(u16* Ks, const float* src, int t) {
  int linear = t;
#pragma unroll
  for (int j = 0; j < 4; ++j, linear += 256) {
    int r = linear >> 4, cq = linear & 15;
    f32x4 v = *(const f32x4*)(src + r * D_DIM + cq * 4);
    int byte = r * 128 + ((cq * 8) ^ ((r & 7) << 4));
    *(u64*)((char*)Ks + byte) =
        (u64)pk2(v[0], v[1]) | ((u64)pk2(v[2], v[3]) << 32);
  }
}
__device__ __forceinline__ void stageV_fn(u16* VTs, const float* src, int t) {
  int kk = t >> 2;
  int dbase = (t & 3) * 16;
  const float* s = src + (size_t)kk * D_DIM + dbase;
#pragma unroll
  for (int j4 = 0; j4 < 4; ++j4) {
    f32x4 v = *(const f32x4*)(s + j4 * 4);
#pragma unroll
    for (int e = 0; e < 4; ++e) {
      int d = dbase + j4 * 4 + e;
      int byte = d * 128 + ((kk * 2) ^ ((d & 7) << 4));
      *(u16*)((char*)VTs + byte) = f2bf(v[e]);
    }
  }
}

// 512-thread staging macros. K tile [64 krows][64 d] f32 -> bf16 swizzled.
#define LOADK_M(ktg_)                                                      \
  {                                                                        \
    const float* src_ = Kg + (size_t)(ktg_)*D_DIM;                         \
    _Pragma("unroll") for (int j = 0; j < 2; ++j) {                        \
      int lin = t + j * 512, r_ = lin >> 4, cq_ = lin & 15;                \
      kreg[j] = *(const f32x4*)(src_ + r_ * D_DIM + cq_ * 4);              \
    }                                                                      \
  }
#define WRITEK_M(buf_)                                                     \
  {                                                                        \
    _Pragma("unroll") for (int j = 0; j < 2; ++j) {                        \
      int lin = t + j * 512, r_ = lin >> 4, cq_ = lin & 15;                \
      int byte_ = r_ * 128 + ((cq_ * 8) ^ ((r_ & 7) << 4));                \
      *(u64*)((char*)(buf_) + byte_) =                                     \
          (u64)pk2(kreg[j][0], kreg[j][1]) |                               \
          ((u64)pk2(kreg[j][2], kreg[j][3]) << 32);                        \
    }                                                                      \
  }
// V tile: 8 k-rows per thread-group (vq=t>>6 in 0..7), lane vd=d (coalesced)
#define LOADV_M(ktg_)                                                      \
  {                                                                        \
    const float* src_ = Vg + (size_t)((ktg_) + vq * 8) * D_DIM + vd;       \
    _Pragma("unroll") for (int j = 0; j < 8; ++j)                          \
        vreg[j] = src_[j * D_DIM];                                         \
  }
#define WRITEV_M(buf_)                                                     \
  {                                                                        \
    uint4 a_;                                                              \
    a_.x = pk2(vreg[0], vreg[1]); a_.y = pk2(vreg[2], vreg[3]);            \
    a_.z = pk2(vreg[4], vreg[5]); a_.w = pk2(vreg[6], vreg[7]);            \
    int swz_ = (vd & 7) << 4;                                              \
    *(uint4*)((char*)(buf_) + vd * 128 + ((vq * 16) ^ swz_)) = a_;         \
  }

// ---------------- kernel 1: partial rowsums (128 q-rows/block) ---------------
__global__ void __launch_bounds__(512) k_rowsum(
    const float* __restrict__ Q, const float* __restrict__ K,
    float* __restrict__ wsRow) {
  __shared__ __align__(16) u16 Ks[2][64 * 64];

  const int t = threadIdx.x, lane = t & 63, w = t >> 6;
  const int cl = lane & 15, lg = lane >> 4;
  const int bx = blockIdx.x;
  const int qt2 = 31 - (bx >> 6);      // heavy first
  const int b = (bx >> 3) & 7;
  const int kc = bx & 7;
  const int q0 = qt2 * 128;
  if (kc * 512 > q0 + 127) return;     // chunk fully above diagonal

  const float* Qg = Q + ((size_t)b * S_LEN + q0) * D_DIM;
  const float* Kg = K + (size_t)b * S_LEN * D_DIM;

  f32x4 kreg[2];
  LOADK_M(kc * 512);                   // tile-0 loads in flight

  const int qrl = w * 16 + cl;         // this lane's q-row (0..127)
  const int qglob = q0 + qrl;
  f32x4 qv0 = *(const f32x4*)(Qg + qrl * D_DIM + lg * 8);
  f32x4 qv1 = *(const f32x4*)(Qg + qrl * D_DIM + lg * 8 + 4);
  f32x4 qv2 = *(const f32x4*)(Qg + qrl * D_DIM + 32 + lg * 8);
  f32x4 qv3 = *(const f32x4*)(Qg + qrl * D_DIM + 32 + lg * 8 + 4);
  bf16x8 bq0 = pack8(qv0, qv1), bq1 = pack8(qv2, qv3);

  const int nt = min(8, ((q0 + 127 - kc * 512) >> 6) + 1);

  WRITEK_M(Ks[0]);
  __syncthreads();

  float psum = 0.f;
  int cur = 0;
  for (int ct64 = 0; ct64 < nt; ++ct64) {
    const int ktg = kc * 512 + ct64 * 64;
    const bool hasNext = (ct64 + 1 < nt);
    if (hasNext) LOADK_M(ktg + 64);
    const u16* Kb = Ks[cur];
#pragma unroll
    for (int ct = 0; ct < 4; ++ct) {
      int krow = ct * 16 + cl;
      int bb0 = krow * 128 + ((lg * 16) ^ ((krow & 7) << 4));
      int bb1 = krow * 128 + ((64 + lg * 16) ^ ((krow & 7) << 4));
      bf16x8 ak0 = *(const bf16x8*)((const char*)Kb + bb0);
      bf16x8 ak1 = *(const bf16x8*)((const char*)Kb + bb1);
      f32x4 c = {0.f, 0.f, 0.f, 0.f};
      c = __builtin_amdgcn_mfma_f32_16x16x32_bf16(ak0, bq0, c, 0, 0, 0);
      c = __builtin_amdgcn_mfma_f32_16x16x32_bf16(ak1, bq1, c, 0, 0, 0);
#pragma unroll
      for (int r = 0; r < 4; ++r) {
        float ev = __expf(c[r] * 0.125f);
        if ((ktg + ct * 16 + lg * 4 + r) > qglob) ev = 0.f;  // causal
        psum += ev;
      }
    }
    if (hasNext) WRITEK_M(Ks[cur ^ 1]);
    __syncthreads();
    cur ^= 1;
  }

  psum += __shfl_xor(psum, 16, 64);
  psum += __shfl_xor(psum, 32, 64);
  const int slot = ((b * 32 + qt2) * 8 + kc);
  if (lg == 0) wsRow[(size_t)slot * 128 + qrl] = psum;
}

// -------- kernel 2: P (LDS-coalesced nt stream) + PV -> O partials / O -------
__global__ void __launch_bounds__(512) k_pwrite_pv(
    const float* __restrict__ Q, const float* __restrict__ K,
    const float* __restrict__ V, const float* __restrict__ wsRow,
    float* __restrict__ Pg, float* __restrict__ wsO,
    float* __restrict__ Og) {
  __shared__ __align__(16) u16 Ks[2][64 * 64];
  __shared__ __align__(16) u16 VTs[2][64 * 64];
  __shared__ __align__(16) u16 Ps[2][128 * 64];

  const int t = threadIdx.x, lane = t & 63, w = t >> 6;
  const int cl = lane & 15, lg = lane >> 4;
  const int bx = blockIdx.x;
  const int qt2 = 31 - (bx >> 6);
  const int b = (bx >> 3) & 7;
  const int kc = bx & 7;
  const int q0 = qt2 * 128;
  float* PgB = Pg + ((size_t)b * S_LEN + q0) * S_LEN + kc * 512;

  if (kc * 512 > q0 + 127) {  // fully above diagonal: pure zero-fill, 256KB
    f32x4 z = {0.f, 0.f, 0.f, 0.f};
    for (int idx = t; idx < 16384; idx += 512)
      nt_store4((float*)((f32x4*)(PgB + (size_t)(idx >> 7) * S_LEN) + (idx & 127)), z);
    return;
  }

  const float* Qg = Q + ((size_t)b * S_LEN + q0) * D_DIM;
  const float* Kg = K + (size_t)b * S_LEN * D_DIM;
  const float* Vg = V + (size_t)b * S_LEN * D_DIM;

  // issue tile-0 staging loads FIRST; zero-fill + rl computation hide them
  f32x4 kreg[2];
  float vreg[8];
  const int vd = t & 63, vq = t >> 6;
  LOADK_M(kc * 512);
  LOADV_M(kc * 512);

  const int nt = min(8, ((q0 + 127 - kc * 512) >> 6) + 1);
  if (nt < 8) {  // zero-fill tail cols [nt*64, 512) for all 128 rows
    const int zc4 = (8 - nt) * 16;  // f32x4 per row (multiple of 16)
    f32x4 z = {0.f, 0.f, 0.f, 0.f};
    for (int r = (t >> 4); r < 128; r += 32) {
      f32x4* rowp = (f32x4*)(PgB + (size_t)r * S_LEN + nt * 64);
      for (int c = (t & 15); c < zc4; c += 16) nt_store4((float*)(rowp + c), z);
    }
  }

  // 1/l for this lane's q-row
  const int nkc = (qt2 >> 2) + 1;
  const float* rowbase = wsRow + (size_t)(b * 32 + qt2) * 8 * 128;
  const int qrl = w * 16 + cl;
  const int qglob = q0 + qrl;
  float ls = 0.f;
  for (int k2 = 0; k2 < nkc; ++k2) ls += rowbase[k2 * 128 + qrl];
  const float rl = 1.0f / ls;

  f32x4 qv0 = *(const f32x4*)(Qg + qrl * D_DIM + lg * 8);
  f32x4 qv1 = *(const f32x4*)(Qg + qrl * D_DIM + lg * 8 + 4);
  f32x4 qv2 = *(const f32x4*)(Qg + qrl * D_DIM + 32 + lg * 8);
  f32x4 qv3 = *(const f32x4*)(Qg + qrl * D_DIM + 32 + lg * 8 + 4);
  bf16x8 bq0 = pack8(qv0, qv1), bq1 = pack8(qv2, qv3);

  WRITEK_M(Ks[0]);
  WRITEV_M(VTs[0]);
  __syncthreads();

  f32x4 oacc[4];
#pragma unroll
  for (int dt = 0; dt < 4; ++dt) oacc[dt] = (f32x4){0.f, 0.f, 0.f, 0.f};

  int cur = 0;
  for (int ct64 = 0; ct64 < nt; ++ct64) {
    const int ktg = kc * 512 + ct64 * 64;
    const bool hasNext = (ct64 + 1 < nt);
    if (hasNext) {  // issue next-tile loads under this tile's compute (T14)
      LOADK_M(ktg + 64);
      LOADV_M(ktg + 64);
    }
    const u16* Kb = Ks[cur];
    const u16* Vb = VTs[cur];
    u16* Psb = Ps[cur];

    // swapped QK^T: lane owns q-row qrl, 4 consecutive k per subtile.
    // Normalized P -> Ps (bf16, packed b64); NO direct global store here.
#pragma unroll
    for (int ct = 0; ct < 4; ++ct) {
      int krow = ct * 16 + cl;
      int bb0 = krow * 128 + ((lg * 16) ^ ((krow & 7) << 4));
      int bb1 = krow * 128 + ((64 + lg * 16) ^ ((krow & 7) << 4));
      bf16x8 ak0 = *(const bf16x8*)((const char*)Kb + bb0);
      bf16x8 ak1 = *(const bf16x8*)((const char*)Kb + bb1);
      f32x4 c = {0.f, 0.f, 0.f, 0.f};
      c = __builtin_amdgcn_mfma_f32_16x16x32_bf16(ak0, bq0, c, 0, 0, 0);
      c = __builtin_amdgcn_mfma_f32_16x16x32_bf16(ak1, bq1, c, 0, 0, 0);
      f32x4 p;
#pragma unroll
      for (int r = 0; r < 4; ++r) {
        float e = __expf(c[r] * 0.125f);
        if ((ktg + ct * 16 + lg * 4 + r) > qglob) e = 0.f;  // causal
        p[r] = e * rl;
      }
      int pbyte = qrl * 128 + (((ct * 32 + lg * 8)) ^ ((qrl & 7) << 4));
      *(u64*)((char*)Psb + pbyte) =
          (u64)pk2(p[0], p[1]) | ((u64)pk2(p[2], p[3]) << 32);
    }

    // PV with normalized P (same-wave rows of Ps[cur]) -> O partials
    {
      int pb0 = qrl * 128 + ((lg * 16) ^ ((qrl & 7) << 4));
      int pb1 = qrl * 128 + ((64 + lg * 16) ^ ((qrl & 7) << 4));
      bf16x8 pa0 = *(const bf16x8*)((const char*)Psb + pb0);
      bf16x8 pa1 = *(const bf16x8*)((const char*)Psb + pb1);
#pragma unroll
      for (int dt = 0; dt < 4; ++dt) {
        int vrow = dt * 16 + cl;
        int vb0 = vrow * 128 + ((lg * 16) ^ ((vrow & 7) << 4));
        int vb1 = vrow * 128 + ((64 + lg * 16) ^ ((vrow & 7) << 4));
        bf16x8 v0 = *(const bf16x8*)((const char*)Vb + vb0);
        bf16x8 v1 = *(const bf16x8*)((const char*)Vb + vb1);
        oacc[dt] = __builtin_amdgcn_mfma_f32_16x16x32_bf16(pa0, v0, oacc[dt], 0, 0, 0);
        oacc[dt] = __builtin_amdgcn_mfma_f32_16x16x32_bf16(pa1, v1, oacc[dt], 0, 0, 0);
      }
    }

    if (hasNext) {  // write prefetched tile AFTER compute (T14)
      WRITEK_M(Ks[cur ^ 1]);
      WRITEV_M(VTs[cur ^ 1]);
    }
    __syncthreads();

    // ---- coalesced nt copy-out of Ps[cur]: 16 lanes/row -> 256B segments.
    // Shares the inter-barrier region with next tile's QK^T (stores drain
    // under MFMA). Safe: next tile writes Ps[cur^1]; Ps[cur] is rewritten
    // only after the NEXT barrier.
#pragma unroll
    for (int j = 0; j < 4; ++j) {
      int slot = j * 512 + t;
      int row = slot >> 4, c4 = slot & 15;
      int byte = row * 128 + ((c4 * 8) ^ ((row & 7) << 4));
      u64 pk = *(const u64*)((const char*)Psb + byte);
      f32x4 o;
      o[0] = bf2f((short)(pk & 0xffff));
      o[1] = bf2f((short)((pk >> 16) & 0xffff));
      o[2] = bf2f((short)((pk >> 32) & 0xffff));
      o[3] = bf2f((short)(pk >> 48));
      nt_store4(PgB + (size_t)row * S_LEN + ct64 * 64 + c4 * 4, o);
    }
    cur ^= 1;
  }

  if (nkc == 1) {
    // single k-chunk: this block owns the whole row -> write O directly
    float* dstO = Og + ((size_t)b * S_LEN + q0) * D_DIM;
#pragma unroll
    for (int dt = 0; dt < 4; ++dt)
#pragma unroll
      for (int r = 0; r < 4; ++r)
        nt_store1(&dstO[(w * 16 + lg * 4 + r) * 64 + dt * 16 + cl], oacc[dt][r]);
  } else {
    const int slot = ((b * 32 + qt2) * 8 + kc);
    float* dstO = wsO + (size_t)slot * 8192;
#pragma unroll
    for (int dt = 0; dt < 4; ++dt)
#pragma unroll
      for (int r = 0; r < 4; ++r)
        nt_store1(&dstO[(w * 16 + lg * 4 + r) * 64 + dt * 16 + cl], oacc[dt][r]);
  }
}

// ---------------- kernel 3: sum O partials (already normalized) --------------
__global__ void __launch_bounds__(256) k_ored(
    const float* __restrict__ wsO, float* __restrict__ Og) {
  const int bx = blockIdx.x;
  const int b = bx & 7, qt2 = bx >> 3;
  const int nkc = (qt2 >> 2) + 1;
  if (nkc == 1) return;  // written directly by k_pwrite_pv
  const int t = threadIdx.x;
  const f32x4* src = (const f32x4*)(wsO + (size_t)(b * 32 + qt2) * 8 * 8192);
  f32x4* dst = (f32x4*)(Og + ((size_t)b * S_LEN + qt2 * 128) * D_DIM);
  for (int i = t; i < 2048; i += 256) {
    f32x4 s = {0.f, 0.f, 0.f, 0.f};
    for (int k2 = 0; k2 < nkc; ++k2)
      s += __builtin_nontemporal_load(src + k2 * 2048 + i);
    nt_store4((float*)(dst + i), s);
  }
}

// ---------------- round-0 fallback (used only if ws too small) ----------------
__global__ void __launch_bounds__(256) attn_kernel(
    const float* __restrict__ Q, const float* __restrict__ K,
    const float* __restrict__ V, float* __restrict__ Og,
    float* __restrict__ Pg) {
  __shared__ __align__(16) u16 Qs[64 * 64];
  __shared__ __align__(16) u16 Ksh[64 * 64];
  __shared__ __align__(16) u16 VTs[64 * 64];
  __shared__ __align__(16) u16 Ps[64 * 64];

  const int t = threadIdx.x;
  const int lane = t & 63;
  const int w = t >> 6;
  const int cl = lane & 15;
  const int lg = lane >> 4;
  const int bx = blockIdx.x;
  const int b = bx & 7;
  const int qb = 63 - (bx >> 3);
  const int q0 = qb * 64;

  const float* Qg = Q + ((size_t)b * S_LEN + q0) * D_DIM;
  const float* Kg = K + (size_t)b * S_LEN * D_DIM;
  const float* Vg = V + (size_t)b * S_LEN * D_DIM;
  float* PgB = Pg + ((size_t)b * S_LEN + q0) * S_LEN;

  {
    int zc4 = (63 - qb) * 16;
    if (zc4 > 0) {
      f32x4 z = {0.f, 0.f, 0.f, 0.f};
      for (int r = 0; r < 64; ++r) {
        f32x4* rowp = (f32x4*)(PgB + (size_t)r * S_LEN + (size_t)(qb + 1) * 64);
        for (int c = t; c < zc4; c += 256) rowp[c] = z;
      }
    }
  }
  stageK_fn(Qs, Qg, t);
  __syncthreads();
  const int qrow = w * 16 + cl;
  bf16x8 aq0, aq1;
  {
    int b0 = qrow * 128 + ((lg * 16) ^ ((qrow & 7) << 4));
    int b1 = qrow * 128 + ((64 + lg * 16) ^ ((qrow & 7) << 4));
    aq0 = *(const bf16x8*)((char*)Qs + b0);
    aq1 = *(const bf16x8*)((char*)Qs + b1);
  }
  float psum[4] = {0.f, 0.f, 0.f, 0.f};
  for (int kt = 0; kt <= qb; ++kt) {
    __syncthreads();
    stageK_fn(Ksh, Kg + (size_t)kt * 64 * D_DIM, t);
    __syncthreads();
#pragma unroll
    for (int ct = 0; ct < 4; ++ct) {
      int krow = ct * 16 + cl;
      int bb0 = krow * 128 + ((lg * 16) ^ ((krow & 7) << 4));
      int bb1 = krow * 128 + ((64 + lg * 16) ^ ((krow & 7) << 4));
      bf16x8 bk0 = *(const bf16x8*)((char*)Ksh + bb0);
      bf16x8 bk1 = *(const bf16x8*)((char*)Ksh + bb1);
      f32x4 c = {0.f, 0.f, 0.f, 0.f};
      c = __builtin_amdgcn_mfma_f32_16x16x32_bf16(aq0, bk0, c, 0, 0, 0);
      c = __builtin_amdgcn_mfma_f32_16x16x32_bf16(aq1, bk1, c, 0, 0, 0);
      int colg = kt * 64 + ct * 16 + cl;
      int rowbase = q0 + w * 16 + lg * 4;
#pragma unroll
      for (int r = 0; r < 4; ++r) {
        float e = 0.f;
        if (colg <= rowbase + r) e = __expf(c[r] * 0.125f);
        psum[r] += e;
      }
    }
  }
  float rl[4];
#pragma unroll
  for (int r = 0; r < 4; ++r) {
    float s = psum[r];
    s += __shfl_xor(s, 1, 64);
    s += __shfl_xor(s, 2, 64);
    s += __shfl_xor(s, 4, 64);
    s += __shfl_xor(s, 8, 64);
    rl[r] = 1.0f / s;
  }
  f32x4 oacc[4];
#pragma unroll
  for (int dt = 0; dt < 4; ++dt) oacc[dt] = (f32x4){0.f, 0.f, 0.f, 0.f};
  for (int kt = 0; kt <= qb; ++kt) {
    __syncthreads();
    stageK_fn(Ksh, Kg + (size_t)kt * 64 * D_DIM, t);
    stageV_fn(VTs, Vg + (size_t)kt * 64 * D_DIM, t);
    __syncthreads();
#pragma unroll
    for (int ct = 0; ct < 4; ++ct) {
      int krow = ct * 16 + cl;
      int bb0 = krow * 128 + ((lg * 16) ^ ((krow & 7) << 4));
      int bb1 = krow * 128 + ((64 + lg * 16) ^ ((krow & 7) << 4));
      bf16x8 bk0 = *(const bf16x8*)((char*)Ksh + bb0);
      bf16x8 bk1 = *(const bf16x8*)((char*)Ksh + bb1);
      f32x4 c = {0.f, 0.f, 0.f, 0.f};
      c = __builtin_amdgcn_mfma_f32_16x16x32_bf16(aq0, bk0, c, 0, 0, 0);
      c = __builtin_amdgcn_mfma_f32_16x16x32_bf16(aq1, bk1, c, 0, 0, 0);
      int colg = kt * 64 + ct * 16 + cl;
      int rowl = w * 16 + lg * 4;
#pragma unroll
      for (int r = 0; r < 4; ++r) {
        float e = 0.f;
        if (colg <= q0 + rowl + r) e = __expf(c[r] * 0.125f);
        float p = e * rl[r];
        int pr = rowl + r;
        int byte = pr * 128 + ((((ct * 16 + cl) * 2)) ^ ((pr & 7) << 4));
        *(u16*)((char*)Ps + byte) = f2bf(p);
      }
    }
    __syncthreads();
    {
      int prow = w * 16 + cl;
      int pb0 = prow * 128 + ((lg * 16) ^ ((prow & 7) << 4));
      int pb1 = prow * 128 + ((64 + lg * 16) ^ ((prow & 7) << 4));
      bf16x8 pa0 = *(const bf16x8*)((char*)Ps + pb0);
      bf16x8 pa1 = *(const bf16x8*)((char*)Ps + pb1);
#pragma unroll
      for (int dt = 0; dt < 4; ++dt) {
        int vrow = dt * 16 + cl;
        int vb0 = vrow * 128 + ((lg * 16) ^ ((vrow & 7) << 4));
        int vb1 = vrow * 128 + ((64 + lg * 16) ^ ((vrow & 7) << 4));
        bf16x8 v0 = *(const bf16x8*)((char*)VTs + vb0);
        bf16x8 v1 = *(const bf16x8*)((char*)VTs + vb1);
        oacc[dt] = __builtin_amdgcn_mfma_f32_16x16x32_bf16(pa0, v0, oacc[dt], 0, 0, 0);
        oacc[dt] = __builtin_amdgcn_mfma_f32_16x16x32_bf16(pa1, v1, oacc[dt], 0, 0, 0);
      }
    }
#pragma unroll
    for (int j = 0; j < 2; ++j) {
      int idx = j * 256 + t;
      int pr = idx >> 3, c8 = idx & 7;
      int byte = pr * 128 + ((c8 * 16) ^ ((pr & 7) << 4));
      bf16x8 pv = *(const bf16x8*)((char*)Ps + byte);
      f32x4 f0, f1;
#pragma unroll
      for (int e = 0; e < 4; ++e) {
        f0[e] = bf2f(pv[e]);
        f1[e] = bf2f(pv[4 + e]);
      }
      f32x4* dst = (f32x4*)(PgB + (size_t)pr * S_LEN + kt * 64 + c8 * 8);
      dst[0] = f0;
      dst[1] = f1;
    }
  }
#pragma unroll
  for (int dt = 0; dt < 4; ++dt)
#pragma unroll
    for (int r = 0; r < 4; ++r)
      Og[((size_t)b * S_LEN + q0 + w * 16 + lg * 4 + r) * D_DIM + dt * 16 + cl] =
          oacc[dt][r];
}

extern "C" void kernel_launch(void* const* d_in, const int* in_sizes, int n_in,
                              void* d_out, int out_size, void* d_ws, size_t ws_size,
                              hipStream_t stream) {
  (void)in_sizes; (void)n_in; (void)out_size;
  const float* Q = (const float*)d_in[0];
  const float* K = (const float*)d_in[1];
  const float* V = (const float*)d_in[2];
  float* Og = (float*)d_out;
  float* Pg = (float*)d_out + (size_t)8 * S_LEN * D_DIM;

  const size_t need = (WSROW_FLOATS + WSO_FLOATS) * sizeof(float);
  if (d_ws != nullptr && ws_size >= need) {
    float* wsRow = (float*)d_ws;
    float* wsO = wsRow + WSROW_FLOATS;
    hipLaunchKernelGGL(k_rowsum, dim3(2048), dim3(512), 0, stream, Q, K, wsRow);
    hipLaunchKernelGGL(k_pwrite_pv, dim3(2048), dim3(512), 0, stream,
                       Q, K, V, wsRow, Pg, wsO, Og);
    hipLaunchKernelGGL(k_ored, dim3(256), dim3(256), 0, stream, wsO, Og);
  } else {
    hipLaunchKernelGGL(attn_kernel, dim3(512), dim3(256), 0, stream, Q, K, V, Og, Pg);
  }
}